// Round 2
// baseline (1108.063 us; speedup 1.0000x reference)
//
#include <hip/hip_runtime.h>

// MaxUnpooling2D sum-scatter:
//   pool: f32 [16,128,128,64]  (64 MiB)
//   ind:  int32 [16,128,128,64] (JAX demoted int64->int32; confirmed by R1 pass)
//   out:  f32 [16,256,256,64]  (256 MiB), zero then out[b*OUT_PER_B + ind] += pool
//
// R1 lesson: grid-stride loop @ VGPR_Count=12 serialized atomics on vmcnt
// (source-reg reuse hazard) -> 810us latency-bound. This round: no loop,
// one thread per vec4 -> max atomics in flight. Plus custom zero kernel
// (hipMemsetAsync blit was ~925 GB/s, ~290us for 256 MiB).

constexpr long long IN_PER_B  = 128LL * 128 * 64;   // 2^20 input elems / batch
constexpr long long OUT_PER_B = 256LL * 256 * 64;   // 2^22 output elems / batch
constexpr long long N         = 16 * IN_PER_B;      // 2^24 input elems total
constexpr int LOG2_IN_PER_B   = 20;

// ---- zero the 256 MiB output: float4 stores, grid-stride ----
__global__ void __launch_bounds__(256) zero_out(float4* __restrict__ out4,
                                               long long n4) {
    const long long stride = (long long)gridDim.x * blockDim.x;
    for (long long i = (long long)blockIdx.x * blockDim.x + threadIdx.x;
         i < n4; i += stride) {
        out4[i] = make_float4(0.f, 0.f, 0.f, 0.f);
    }
}

// ---- scatter: one thread per vec4, no loop, fire-and-forget atomics ----
__global__ void __launch_bounds__(256) unpool_scatter(
        const float4* __restrict__ pool4,
        const int4*   __restrict__ ind4,
        float*        __restrict__ out) {
    const long long i = (long long)blockIdx.x * blockDim.x + threadIdx.x;
    // grid sized exactly: N/4 threads
    const float4 v  = pool4[i];
    const int4   id = ind4[i];
    // 4 consecutive input elems share a batch (IN_PER_B % 4 == 0)
    const long long bofs = ((i << 2) >> LOG2_IN_PER_B) * OUT_PER_B;
    atomicAdd(&out[bofs + (long long)id.x], v.x);
    atomicAdd(&out[bofs + (long long)id.y], v.y);
    atomicAdd(&out[bofs + (long long)id.z], v.z);
    atomicAdd(&out[bofs + (long long)id.w], v.w);
}

extern "C" void kernel_launch(void* const* d_in, const int* in_sizes, int n_in,
                              void* d_out, int out_size, void* d_ws, size_t ws_size,
                              hipStream_t stream) {
    const float* pool = (const float*)d_in[0];
    const int*   ind  = (const int*)d_in[1];
    float*       out  = (float*)d_out;

    // zero 256 MiB output (harness re-poisons to 0xAA before every call)
    const long long out_n4 = (long long)out_size >> 2;       // 16,777,216 float4
    zero_out<<<4096, 256, 0, stream>>>((float4*)out, out_n4);

    // scatter: N/4 = 4,194,304 threads = 16384 blocks x 256
    const long long n4 = N >> 2;
    const int blocks = (int)(n4 / 256);                      // exact division
    unpool_scatter<<<blocks, 256, 0, stream>>>(
        (const float4*)pool, (const int4*)ind, out);
}